// Round 1
// baseline (6778.030 us; speedup 1.0000x reference)
//
#include <hip/hip_runtime.h>
#include <cstdint>
#include <cstddef>

// Seq2Seq LSTM (B=32,S=T=64,E=256,H=512,V=32000), fp32 baseline.
// Design notes:
//  - 320-stage sequential chain -> one kernel per cell / fc / argmax (R1 baseline;
//    persistent kernel planned later).
//  - Cell kernel: grid 256 WGs, each WG owns 2 j-columns x 4 gates (8 rows of the
//    4H=2048 z-rows) for ALL 32 batch rows. W rows staged to LDS once (no 32x
//    batch re-read). Lane = (b_local*8 + kq): kq slices K into 8 register-resident
//    chunks; shfl_xor(1,2,4) reduces. kq chunk strides padded (+4 floats) so the 8
//    kq start banks are distinct -> conflict-free ds_read_b128.
//  - h ping-pong per step (cross-WG h reads vs writes); c in-place (elementwise).
//  - fc kernel: 1000 WGs x 32 v-rows, same lane layout, W chunk staged to LDS
//    (69.6KB -> 2 WGs/CU), per-lane running argmax (first-index tie-break) ->
//    2-level argmax matching jnp.argmax semantics.

#define BSZ  32
#define SLEN 64
#define TLEN 64
#define EDIM 256
#define HDIM 512
#define VOUT 32000
#define FCCH 32
#define NFCWG (VOUT / FCCH)   // 1000

// ---------------------------------------------------------------- LSTM cell ---
template<int KIN>
__global__ __launch_bounds__(256)
void cell_k(const float* __restrict__ xbase, const int* __restrict__ xidx,
            int xstride, int xoff,
            const float* __restrict__ Wih, const float* __restrict__ Whh,
            const float* __restrict__ bih, const float* __restrict__ bhh,
            const float* __restrict__ hin, float* __restrict__ hout,
            float* __restrict__ cbuf,
            const int* __restrict__ lens, int s)
{
    constexpr int XC = KIN / 8;       // per-lane x floats
    constexpr int XS = XC + 4;        // padded chunk stride (bank spread)
    constexpr int HS = 64 + 4;
    constexpr int RS = 8 * XS + 8 * HS;
    __shared__ __align__(16) float wsm[8 * RS];
    __shared__ float zsh[8][32];

    const int tid = threadIdx.x;
    const int j0  = blockIdx.x * 2;

    // ---- stage 8 weight rows [Wih | Whh] into LDS (each row staged once/cell)
    {
        const int nf4x = KIN / 4;
        for (int t = tid; t < 8 * nf4x; t += 256) {
            int r = t / nf4x, k = (t % nf4x) * 4;
            int row = (r >> 1) * HDIM + j0 + (r & 1);
            float4 v = *(const float4*)(Wih + (size_t)row * KIN + k);
            *(float4*)(wsm + r * RS + (k / XC) * XS + (k % XC)) = v;
        }
        for (int t = tid; t < 8 * 128; t += 256) {
            int r = t >> 7, k = (t & 127) * 4;
            int row = (r >> 1) * HDIM + j0 + (r & 1);
            float4 v = *(const float4*)(Whh + (size_t)row * HDIM + k);
            *(float4*)(wsm + r * RS + 8 * XS + (k >> 6) * HS + (k & 63)) = v;
        }
    }

    // ---- per-lane x/h register slices
    const int wv = tid >> 6, lane = tid & 63;
    const int bl = lane >> 3, kq = lane & 7;
    const int b  = wv * 8 + bl;

    const float* xrow = xidx ? xbase + (size_t)xidx[b * xstride + xoff] * KIN
                             : xbase + (size_t)b * KIN;
    float4 xr[XC / 4];
#pragma unroll
    for (int i = 0; i < XC / 4; i++)
        xr[i] = *(const float4*)(xrow + kq * XC + i * 4);
    float4 hr[16];
    const float* hrow = hin + (size_t)b * HDIM + kq * 64;
#pragma unroll
    for (int i = 0; i < 16; i++)
        hr[i] = *(const float4*)(hrow + i * 4);

    __syncthreads();

    // ---- 8 rows: dot(K) via kq-sliced FMAs + shfl reduce over kq
#pragma unroll
    for (int r = 0; r < 8; r++) {
        float acc = 0.f;
        const float* wx = wsm + r * RS + kq * XS;
#pragma unroll
        for (int i = 0; i < XC / 4; i++) {
            float4 w = *(const float4*)(wx + i * 4);
            acc += w.x * xr[i].x + w.y * xr[i].y + w.z * xr[i].z + w.w * xr[i].w;
        }
        const float* wh = wsm + r * RS + 8 * XS + kq * HS;
#pragma unroll
        for (int i = 0; i < 16; i++) {
            float4 w = *(const float4*)(wh + i * 4);
            acc += w.x * hr[i].x + w.y * hr[i].y + w.z * hr[i].z + w.w * hr[i].w;
        }
        acc += __shfl_xor(acc, 1);
        acc += __shfl_xor(acc, 2);
        acc += __shfl_xor(acc, 4);
        if (kq == 0) zsh[r][b] = acc;
    }
    __syncthreads();

    // ---- gates + state update (2 j x 32 b per WG)
    if (tid < 64) {
        int jl = tid >> 5, bb = tid & 31;
        int j  = j0 + jl;
        float zi = zsh[0 + jl][bb] + bih[0 * HDIM + j] + bhh[0 * HDIM + j];
        float zf = zsh[2 + jl][bb] + bih[1 * HDIM + j] + bhh[1 * HDIM + j];
        float zg = zsh[4 + jl][bb] + bih[2 * HDIM + j] + bhh[2 * HDIM + j];
        float zo = zsh[6 + jl][bb] + bih[3 * HDIM + j] + bhh[3 * HDIM + j];
        float iv = 1.f / (1.f + expf(-zi));
        float fv = 1.f / (1.f + expf(-zf));
        float gv = tanhf(zg);
        float ov = 1.f / (1.f + expf(-zo));
        size_t off = (size_t)bb * HDIM + j;
        float cold = cbuf[off];
        float c2 = fv * cold + iv * gv;
        float h2 = ov * tanhf(c2);
        bool m = lens ? (s < lens[bb]) : true;
        hout[off] = m ? h2 : hin[off];
        cbuf[off] = m ? c2 : cold;
    }
}

// --------------------------------------------------------------------- fc ----
__global__ __launch_bounds__(256)
void fc_k(const float* __restrict__ h, const float* __restrict__ fcW,
          const float* __restrict__ fcb, float* __restrict__ out, int t,
          float* __restrict__ cand_val, int* __restrict__ cand_idx)
{
    __shared__ __align__(16) float wsm[FCCH * 544];  // [v][8 kq][68]
    __shared__ float ls[FCCH * 33];                  // [v_local][b]
    const int tid = threadIdx.x;
    const int g   = blockIdx.x;
    const int v0  = g * FCCH;

    for (int ti = tid; ti < FCCH * 128; ti += 256) {
        int vl = ti >> 7, k = (ti & 127) * 4;
        float4 w = *(const float4*)(fcW + (size_t)(v0 + vl) * HDIM + k);
        *(float4*)(wsm + vl * 544 + (k >> 6) * 68 + (k & 63)) = w;
    }

    const int wv = tid >> 6, lane = tid & 63;
    const int bl = lane >> 3, kq = lane & 7;
    const int b  = wv * 8 + bl;
    float4 hr[16];
    const float* hrow = h + (size_t)b * HDIM + kq * 64;
#pragma unroll
    for (int i = 0; i < 16; i++) hr[i] = *(const float4*)(hrow + i * 4);

    __syncthreads();

    float mval = -3.4e38f; int midx = 0;
    for (int vl = 0; vl < FCCH; vl++) {
        float acc = 0.f;
        const float* wp = wsm + vl * 544 + kq * 68;
#pragma unroll
        for (int i = 0; i < 16; i++) {
            float4 w = *(const float4*)(wp + i * 4);
            acc += w.x * hr[i].x + w.y * hr[i].y + w.z * hr[i].z + w.w * hr[i].w;
        }
        acc += __shfl_xor(acc, 1);
        acc += __shfl_xor(acc, 2);
        acc += __shfl_xor(acc, 4);
        if (kq == 0) {
            acc += fcb[v0 + vl];
            ls[vl * 33 + b] = acc;
            if (acc > mval) { mval = acc; midx = v0 + vl; }  // ascending v: '>' keeps first max
        }
    }
    __syncthreads();

    // coalesced logits write: 8 threads per b, 4 consecutive v each
    {
        int bb = tid >> 3, c8 = tid & 7;
        float tmp[4];
#pragma unroll
        for (int ii = 0; ii < 4; ii++)
            tmp[ii] = ls[(c8 * 4 + ii) * 33 + bb];
        float* op = out + ((size_t)bb * TLEN + t) * VOUT + v0 + c8 * 4;
        *(float4*)op = make_float4(tmp[0], tmp[1], tmp[2], tmp[3]);
    }
    if (kq == 0) {
        cand_val[b * NFCWG + g] = mval;
        cand_idx[b * NFCWG + g] = midx;
    }
}

// ----------------------------------------------------------------- argmax ----
__global__ __launch_bounds__(256)
void argmax_k(const float* __restrict__ cand_val, const int* __restrict__ cand_idx,
              int* __restrict__ tok)
{
    __shared__ float sv[256];
    __shared__ int   si[256];
    int b = blockIdx.x, tid = threadIdx.x;
    float bv = -3.4e38f; int bi = 0x7fffffff;
    for (int gg = tid; gg < NFCWG; gg += 256) {
        float v = cand_val[b * NFCWG + gg];
        int  ix = cand_idx[b * NFCWG + gg];
        if (v > bv || (v == bv && ix < bi)) { bv = v; bi = ix; }
    }
    sv[tid] = bv; si[tid] = bi;
    __syncthreads();
    for (int stp = 128; stp > 0; stp >>= 1) {
        if (tid < stp) {
            float v = sv[tid + stp]; int ix = si[tid + stp];
            if (v > sv[tid] || (v == sv[tid] && ix < si[tid])) { sv[tid] = v; si[tid] = ix; }
        }
        __syncthreads();
    }
    if (tid == 0) tok[b] = si[0];
}

// ------------------------------------------------------------------- init ----
__global__ void init_enc(float* h0a, float* h1a, float* c0, float* c1)
{
    int i = blockIdx.x * 256 + threadIdx.x;
    if (i < BSZ * HDIM) { h0a[i] = 0.f; h1a[i] = 0.f; c0[i] = 0.f; c1[i] = 0.f; }
}
__global__ void init_dec(float* c0, float* c1, int* tok)
{
    int i = blockIdx.x * 256 + threadIdx.x;
    if (i < BSZ * HDIM) { c0[i] = 0.f; c1[i] = 0.f; }
    if (i < BSZ) tok[i] = 1;
}

// ----------------------------------------------------------------- driver ----
extern "C" void kernel_launch(void* const* d_in, const int* in_sizes, int n_in,
                              void* d_out, int out_size, void* d_ws, size_t ws_size,
                              hipStream_t stream)
{
    const int*   inputs  = (const int*)d_in[0];
    // d_in[1] targets: unused by reference
    const int*   lens    = (const int*)d_in[3];
    const float* enc_emb = (const float*)d_in[4];
    const float* dec_emb = (const float*)d_in[5];
    const float* W[16];
    for (int i = 0; i < 16; i++) W[i] = (const float*)d_in[6 + i];
    // W[0..7]  = enc: Wih0,Whh0,bih0,bhh0,Wih1,Whh1,bih1,bhh1
    // W[8..15] = dec: same order
    const float* fcW = (const float*)d_in[22];
    const float* fcb = (const float*)d_in[23];
    float* out = (float*)d_out;

    float* ws = (float*)d_ws;
    float* h0[2]    = { ws,          ws + 16384 };
    float* h1[2]    = { ws + 32768,  ws + 49152 };
    float* c0       = ws + 65536;
    float* c1       = ws + 81920;
    float* cand_val = ws + 98304;                 // 32*1000
    int*   cand_idx = (int*)(ws + 98304 + 32000); // 32*1000
    int*   tok      = (int*)(ws + 98304 + 64000); // 32

    init_enc<<<64, 256, 0, stream>>>(h0[0], h1[0], c0, c1);
    for (int s = 0; s < SLEN; s++) {
        int p = s & 1;
        cell_k<EDIM><<<256, 256, 0, stream>>>(enc_emb, inputs, SLEN, s,
            W[0], W[1], W[2], W[3], h0[p], h0[p ^ 1], c0, lens, s);
        cell_k<HDIM><<<256, 256, 0, stream>>>(h0[p ^ 1], nullptr, 0, 0,
            W[4], W[5], W[6], W[7], h1[p], h1[p ^ 1], c1, lens, s);
    }
    init_dec<<<64, 256, 0, stream>>>(c0, c1, tok);
    for (int t = 0; t < TLEN; t++) {
        int p = t & 1;
        cell_k<EDIM><<<256, 256, 0, stream>>>(dec_emb, tok, 1, 0,
            W[8], W[9], W[10], W[11], h0[p], h0[p ^ 1], c0, nullptr, 0);
        cell_k<HDIM><<<256, 256, 0, stream>>>(h0[p ^ 1], nullptr, 0, 0,
            W[12], W[13], W[14], W[15], h1[p], h1[p ^ 1], c1, nullptr, 0);
        fc_k<<<NFCWG, 256, 0, stream>>>(h1[p ^ 1], fcW, fcb, out, t, cand_val, cand_idx);
        argmax_k<<<BSZ, 256, 0, stream>>>(cand_val, cand_idx, tok);
    }
}